// Round 4
// baseline (208.883 us; speedup 1.0000x reference)
//
#include <hip/hip_runtime.h>

#define V 200000
#define R 100
#define D 128
#define K 20
#define B 128
#define N 50

// ---------------------------------------------------------------------------
// Kernel 1 (fused rel-score + logits + exp):
//   att_e[(n*K+k)*B + b] = exp(relu(ee.W0 + ne.W1 + nr.W2 + b_att))
// Logits are post-relu (>= 0, bounded ~6), so exp without max-subtraction is
// numerically safe and identical to softmax-with-max up to f32 rounding.
// 256 threads = 4 waves; each wave owns one (b,n) pair; 4 groups of 16 lanes
// per wave, each group one neighbor row per iteration (all 20 gathers in
// flight per wave).
// ---------------------------------------------------------------------------
__global__ void k_logits(const int* __restrict__ eids,
                         const int* __restrict__ adjE,
                         const int* __restrict__ adjR,
                         const float* __restrict__ EE,
                         const float* __restrict__ RE,
                         const float* __restrict__ Watt,
                         const float* __restrict__ batt,
                         float* __restrict__ att_e) {
  const int lane = threadIdx.x & 63;
  const int wv   = threadIdx.x >> 6;
  const int bn   = blockIdx.x * 4 + wv;     // 0 .. B*N-1
  const int b = bn / N;
  const int n = bn % N;
  const int eid = eids[bn];

  // --- ee . W0 (full wave, float2/lane) ---
  const float2 wa_e = ((const float2*)Watt)[lane];
  const float2 e2   = ((const float2*)(EE + (size_t)eid * D))[lane];
  float p = e2.x * wa_e.x + e2.y * wa_e.y;
  #pragma unroll
  for (int off = 32; off > 0; off >>= 1) p += __shfl_down(p, off);
  const float s_ee = __shfl(p, 0) + batt[0];

  // --- neighbor dots: 16-lane groups ---
  const int g  = lane >> 4;                 // 0..3
  const int sl = lane & 15;                 // 0..15, covers dims 8*sl..8*sl+7
  const float4* wnp = (const float4*)(Watt + D + 8 * sl);
  const float4* wrp = (const float4*)(Watt + 2 * D + 8 * sl);
  const float4 wn0 = wnp[0], wn1 = wnp[1];
  const float4 wr0 = wrp[0], wr1 = wrp[1];

  const int* ae = adjE + eid * K;
  const int* ar = adjR + eid * K;

  float q[5];
  #pragma unroll
  for (int k5 = 0; k5 < 5; ++k5) {
    const int k = k5 * 4 + g;
    const int nid = ae[k];
    const int rid = ar[k];
    const float4* np = (const float4*)(EE + (size_t)nid * D + 8 * sl);
    const float4* rp = (const float4*)(RE + (size_t)rid * D + 8 * sl);
    const float4 n0 = np[0], n1 = np[1];
    const float4 r0 = rp[0], r1 = rp[1];
    float s = n0.x * wn0.x + n0.y * wn0.y + n0.z * wn0.z + n0.w * wn0.w
            + n1.x * wn1.x + n1.y * wn1.y + n1.z * wn1.z + n1.w * wn1.w
            + r0.x * wr0.x + r0.y * wr0.y + r0.z * wr0.z + r0.w * wr0.w
            + r1.x * wr1.x + r1.y * wr1.y + r1.z * wr1.z + r1.w * wr1.w;
    #pragma unroll
    for (int off = 8; off > 0; off >>= 1) s += __shfl_down(s, off, 16);
    q[k5] = s;
  }

  if (sl == 0) {
    #pragma unroll
    for (int k5 = 0; k5 < 5; ++k5) {
      const int k = k5 * 4 + g;
      const float logit = s_ee + q[k5];
      const float rl = logit > 0.0f ? logit : 0.0f;
      att_e[(n * K + k) * B + b] = __expf(rl);
    }
  }
}

// ---------------------------------------------------------------------------
// Kernel 2: inv_sum[g] = 1 / sum_b att_e[g*B + b].  One wave per (n,k) group,
// 4 groups per 256-thread block; float2 per lane.
// ---------------------------------------------------------------------------
__global__ void k_sum(const float* __restrict__ att_e,
                      float* __restrict__ inv_sum) {
  const int g    = blockIdx.x * 4 + (threadIdx.x >> 6);  // 0 .. N*K-1
  const int lane = threadIdx.x & 63;
  const float2 e2 = ((const float2*)(att_e + g * B))[lane];
  float s = e2.x + e2.y;
  #pragma unroll
  for (int off = 32; off > 0; off >>= 1) s += __shfl_down(s, off);
  if (lane == 0) inv_sum[g] = 1.0f / s;
}

// ---------------------------------------------------------------------------
// Kernel 3: neighbor_att + epilogue GEMV.
// G=16 pairs per block (W_conv read once per block -> 52 MB total from L2),
// 256 threads = (d 0..127) x (h 0..1); phase 2 splits the 2D inner product
// across h. Attention weight = att_e * inv_sum folded into staging.
// ---------------------------------------------------------------------------
#define G 16
__global__ void k_out(const int* __restrict__ eids,
                      const int* __restrict__ adjE,
                      const float* __restrict__ EE,
                      const float* __restrict__ att_e,
                      const float* __restrict__ inv_sum,
                      const float* __restrict__ Wc,
                      const float* __restrict__ bc,
                      float* __restrict__ out) {
  __shared__ float agg[G][2 * D];        // 16 KB
  __shared__ float part[2][G][D];        // 16 KB
  __shared__ float s_att[G][K];
  __shared__ int   s_nid[G][K];

  const int t = threadIdx.x;             // 0 .. 255
  const int d = t & 127;
  const int h = t >> 7;
  const int base = blockIdx.x * G;

  // stage neighbor ids + normalized attention scalars
  for (int s = t; s < G * K; s += 256) {
    const int j = s / K, k = s % K;
    const int bn = base + j;
    const int b = bn / N;
    const int n = bn % N;
    const int eid = eids[bn];
    const int g = n * K + k;
    s_nid[j][k] = adjE[eid * K + k];
    s_att[j][k] = att_e[g * B + b] * inv_sum[g];
  }
  __syncthreads();

  // phase 1: gather + weighted sum; half h covers pairs j = h, h+2, ...
  #pragma unroll
  for (int jj = 0; jj < G / 2; ++jj) {
    const int j = h + jj * 2;
    const int bn = base + j;
    const int eid = eids[bn];
    const float ee = EE[(size_t)eid * D + d];
    float na = 0.0f;
    #pragma unroll
    for (int k = 0; k < K; ++k)
      na += s_att[j][k] * EE[(size_t)s_nid[j][k] * D + d];
    agg[j][d] = ee;
    agg[j][D + d] = na;
  }
  __syncthreads();

  // phase 2: partial GEMV over i in [128h, 128h+128), all G pairs
  float acc[G];
  #pragma unroll
  for (int j = 0; j < G; ++j) acc[j] = 0.0f;
  const int ibase = h * D;
  for (int c = 0; c < 32; ++c) {
    const int i = ibase + c * 4;
    const float w0 = Wc[(i + 0) * D + d];
    const float w1 = Wc[(i + 1) * D + d];
    const float w2 = Wc[(i + 2) * D + d];
    const float w3 = Wc[(i + 3) * D + d];
    #pragma unroll
    for (int j = 0; j < G; ++j) {
      const float4 a = *(const float4*)&agg[j][i];   // same-address broadcast
      acc[j] += a.x * w0 + a.y * w1 + a.z * w2 + a.w * w3;
    }
  }
  #pragma unroll
  for (int j = 0; j < G; ++j) part[h][j][d] = acc[j];
  __syncthreads();

  // combine halves + bias + relu
  const float bb = bc[d];
  #pragma unroll
  for (int jj = 0; jj < G / 2; ++jj) {
    const int j = h + jj * 2;
    const float v = part[0][j][d] + part[1][j][d] + bb;
    out[(size_t)(base + j) * D + d] = v > 0.0f ? v : 0.0f;
  }
}

// ---------------------------------------------------------------------------
extern "C" void kernel_launch(void* const* d_in, const int* in_sizes, int n_in,
                              void* d_out, int out_size, void* d_ws, size_t ws_size,
                              hipStream_t stream) {
  const int*   eids = (const int*)d_in[0];      // [B*N]
  const int*   adjE = (const int*)d_in[1];      // [V*K]
  const int*   adjR = (const int*)d_in[2];      // [V*K]
  const float* EE   = (const float*)d_in[3];    // [V*D]
  const float* RE   = (const float*)d_in[4];    // [R*D]
  const float* Watt = (const float*)d_in[5];    // [3*D]
  const float* batt = (const float*)d_in[6];    // [1]
  const float* Wc   = (const float*)d_in[7];    // [2*D*D]
  const float* bc   = (const float*)d_in[8];    // [D]
  float* out = (float*)d_out;

  float* att_e   = (float*)d_ws;                // N*K*B floats (1 MB)
  float* inv_sum = att_e + (size_t)N * K * B;   // N*K floats

  k_logits<<<(B * N) / 4, 256, 0, stream>>>(eids, adjE, adjR, EE, RE, Watt,
                                            batt, att_e);
  k_sum<<<(N * K) / 4, 256, 0, stream>>>(att_e, inv_sum);
  k_out<<<(B * N) / G, 256, 0, stream>>>(eids, adjE, EE, att_e, inv_sum,
                                         Wc, bc, out);
}